// Round 10
// baseline (3955.772 us; speedup 1.0000x reference)
//
#include <hip/hip_runtime.h>
#include <hip/hip_bf16.h>

// GRU-imputation scan (B=128,T=128,D=128,H=1024,L=3), f32 in/out.
// Round 12: R=32 repartition of the 384-kernel chain. Block = (rg 0..3) x
// (jj 0..63): 32 rows x 16 output cols, all 4 gates in-block. Per-block
// traffic drops 288 -> 192 KB (weights halve, h-stage doubles but is
// L2-cached). bid%8 == jj%8 keeps weight<->XCD L2 affinity. 256 blocks x
// 512 threads; validated fragment layout, two 16-row halves (rt).

typedef __hip_bfloat16 bf16;
typedef unsigned int u32;
typedef unsigned short u16;
typedef __attribute__((ext_vector_type(8))) short v8bf;   // 8 x bf16 (16B)
typedef __attribute__((ext_vector_type(4))) float v4f;    // MFMA C/D
typedef __attribute__((ext_vector_type(4))) u32 v4u;

__device__ __forceinline__ float bf2f(bf16 v){ return __bfloat162float(v); }
__device__ __forceinline__ bf16 f2bf(float v){ return __float2bfloat16(v); }
__device__ __forceinline__ float sigm(float x){ return 1.f/(1.f + __expf(-x)); }
__device__ __forceinline__ float tanh_(float x){
  float a = fminf(fmaxf(x, -15.f), 15.f);
  float t = __expf(2.f*a);
  return (t-1.f)/(t+1.f);
}
__device__ __forceinline__ v8bf ldv(const bf16* p){ return *reinterpret_cast<const v8bf*>(p); }

// =================================================================
// Packing kernels (unchanged; validated).
// Fragment unit = 64 lanes x 8 bf16; lane's 8 elems =
//   W[row(j,lane&15)][kk*32 + ((lane>>4)&3)*8 + e]
// =================================================================
__global__ void pack_upper_k(const float* __restrict__ Wih, const float* __restrict__ Whh,
                             bf16* __restrict__ dst){
  int tid = blockIdx.x*256 + threadIdx.x;          // 1,048,576
  int lane = tid & 63;
  int u    = tid >> 6;
  int kk   = u & 31;
  int j    = (u >> 5) & 63;
  int s    = (u >> 11) & 3;
  int l    = u >> 13;
  int n    = j*16 + (lane & 15);
  int k    = kk*32 + ((lane>>4)&3)*8;
  int row  = (s==0) ? n : (s==1 ? 1024+n : 2048+n);
  size_t src = ((size_t)l*3072 + row)*1024 + k;
  size_t o = (size_t)tid*8;
  #pragma unroll
  for (int e=0;e<8;e++){
    float v;
    if (s < 2)      v = Wih[src+e] + Whh[src+e];
    else if (s==2)  v = Wih[src+e];
    else            v = Whh[src+e];
    dst[o+e] = f2bf(v);
  }
}
__global__ void pack_l0h_k(const float* __restrict__ Whh0, bf16* __restrict__ dst){
  int tid = blockIdx.x*256 + threadIdx.x;          // 393,216
  int lane = tid & 63;
  int u  = tid >> 6;
  int kk = u & 31;
  int j  = (u >> 5) & 63;
  int g  = u >> 11;
  int row = g*1024 + j*16 + (lane&15);
  int k   = kk*32 + ((lane>>4)&3)*8;
  size_t src = (size_t)row*1024 + k;
  size_t o = (size_t)tid*8;
  #pragma unroll
  for (int e=0;e<8;e++) dst[o+e] = f2bf(Whh0[src+e]);
}
__global__ void pack_l0x_k(const float* __restrict__ Wih0, bf16* __restrict__ dst){
  int tid = blockIdx.x*256 + threadIdx.x;          // 49,152
  int lane = tid & 63;
  int u  = tid >> 6;
  int kk = u & 3;
  int j  = (u >> 2) & 63;
  int g  = u >> 8;
  int row = g*1024 + j*16 + (lane&15);
  int k   = kk*32 + ((lane>>4)&3)*8;
  size_t src = (size_t)row*128 + k;
  size_t o = (size_t)tid*8;
  #pragma unroll
  for (int e=0;e<8;e++) dst[o+e] = f2bf(Wih0[src+e]);
}
__global__ void pack_imp_k(const float* __restrict__ Wp, bf16* __restrict__ dst){
  int tid = blockIdx.x*256 + threadIdx.x;          // 16,384
  int lane = tid & 63;
  int u  = tid >> 6;
  int kk = u & 31;
  int jj = u >> 5;
  int row = jj*16 + (lane&15);
  int k   = kk*32 + ((lane>>4)&3)*8;
  size_t src = (size_t)row*1024 + k;
  size_t o = (size_t)tid*8;
  #pragma unroll
  for (int e=0;e<8;e++) dst[o+e] = f2bf(Wp[src+e]);
}
__global__ void init_pk(bf16* __restrict__ hA){
  int tid = blockIdx.x*256 + threadIdx.x;          // 131,072
  hA[tid] = f2bf(0.f);                             // h0 = 0
}

// =================================================================
// LDS fragment layout (validated), extended to 32 rows as two 16-row
// halves rt=0,1: lds_h[rt*16384 + kk*512 + lane*8] holds
// h[rt*16 + lane&15][kk*32 + (lane>>4)*8 + e].
// =================================================================
__device__ __forceinline__ v8bf afrag32(const bf16* lds_h, int rt, int kk, int lane){
  return ldv(lds_h + (size_t)rt*16384 + (size_t)kk*512 + (size_t)lane*8);
}
__device__ __forceinline__ float hp32(const bf16* lds_h, int rl, int colh){
  int rt = rl >> 4, lr = rl & 15;
  int kk = colh >> 5, q = (colh >> 3) & 3, e = colh & 7;
  return bf2f(lds_h[(size_t)rt*16384 + (size_t)kk*512 + (size_t)(q*16 + lr)*8 + e]);
}

#define MFMA(a,b,c) __builtin_amdgcn_mfma_f32_16x16x32_bf16((a),(b),(c),0,0,0)

// lds2 tile: 16x16 f32 at stride 17 (pad), tile stride 272
#define T_W(w, row, col)  lds2[(w)*272 + (row)*17 + (col)]

// stage 32 rows x 1024 cols of h -> fragment LDS; 8 waves:
// rt = w>>2, kq = w&3 -> units kk = kq*8 .. kq*8+7 of half rt.
__device__ __forceinline__ void stage32(const bf16* __restrict__ src_rg, bf16* lds_h,
                                        int wave, int lane, int l15, int quad){
  const int rt = wave >> 2, kq = wave & 3;
  const bf16* g0 = src_rg + (size_t)(rt*16 + l15)*1024 + kq*256 + quad*8;
  bf16* d0 = lds_h + (size_t)rt*16384 + (size_t)(kq*8)*512 + (size_t)lane*8;
  #pragma unroll
  for (int i=0;i<8;++i){
    v4u r = *(const v4u*)(g0 + i*32);
    *(v4u*)(d0 + i*512) = r;
  }
}

// lds_c: comp slice, 32 rows x 128 d as two halves:
// lds_c[rt*2048 + (d>>5)*512 + ((d>>3)&3)*128 + (rl&15)*8 + (d&7)]
__device__ __forceinline__ size_t cidx(int rt, int lr, int d){
  return (size_t)rt*2048 + (size_t)(d>>5)*512 + (size_t)(((d>>3)&3)*16 + lr)*8 + (d&7);
}

// =================================================================
// L0 kernel (one timestep): fused IC(t-1) + hB = GRU0(comp(t-1), hA).
// Grid 256 x 512: jj = bid&63 (16 cols, jj%8 = XCD), rg = bid>>6 (32 rows).
// =================================================================
__global__ __launch_bounds__(512) void gru_l0(
  const int t,
  const float* __restrict__ x, const float* __restrict__ masks,
  const float* __restrict__ bih0, const float* __restrict__ bhh0,
  const float* __restrict__ bp,
  const bf16* __restrict__ packL0h, const bf16* __restrict__ packL0x,
  const bf16* __restrict__ packImp,
  const bf16* __restrict__ hA, bf16* __restrict__ hB,
  float* __restrict__ out)
{
  const int tid  = threadIdx.x;
  const int lane = tid & 63;
  const int wave = tid >> 6;           // 0..7
  const int l15  = lane & 15;
  const int quad = lane >> 4;
  const int bid  = blockIdx.x;
  const int jj   = bid & 63;
  const int rg   = bid >> 6;
  const int rB   = rg * 32;

  __shared__ bf16 lds_h[32768];        // 64 KB staged h slice (32 x 1024)
  __shared__ bf16 lds_c[4096];         // 8 KB staged comp slice (32 x 128)
  __shared__ float lds2[16*272];       // ~17.4 KB partial tiles (padded)

  stage32(hA + (size_t)rB*1024, lds_h, wave, lane, l15, quad);
  __syncthreads();

  // ---- fused IC: build comp(t-1) slice into lds_c; write out for t>=1 ----
  if (t == 0){
    // comp(-1) = x[:, 0, :]; thread rl = tid>>4 (32 rows), c = tid&15 -> 8 d
    const int rl = tid >> 4, c = tid & 15;
    const int rt = rl >> 4, lr = rl & 15;
    #pragma unroll
    for (int k=0;k<8;++k){
      const int d = c*8 + k;
      float v = x[(size_t)(rB+rl)*16384 + d];
      lds_c[cidx(rt, lr, d)] = f2bf(v);
    }
  } else {
    // imp(t-1)[32,128] = lds_h @ Wp^T + bp, redundant per block.
    // wave: rt = w>>2, dp = w&3 -> d-tiles jt = 2dp, 2dp+1 (full K each).
    {
      const int rt = wave >> 2, dp = wave & 3;
      #pragma unroll
      for (int u2=0; u2<2; ++u2){
        const int jt = dp*2 + u2;
        v4f a0 = {0.f,0.f,0.f,0.f}, a1 = {0.f,0.f,0.f,0.f};
        const bf16* wp = packImp + ((size_t)(jt*32))*512 + lane*8;
        #pragma unroll
        for (int i=0;i<32;i+=2){
          a0 = MFMA(afrag32(lds_h, rt, i,   lane), ldv(wp + (size_t)i*512),     a0);
          a1 = MFMA(afrag32(lds_h, rt, i+1, lane), ldv(wp + (size_t)(i+1)*512), a1);
        }
        const v4f a = a0 + a1;
        #pragma unroll
        for (int r=0;r<4;r++) T_W(rt*8 + jt, quad*4+r, l15) = a[r];
      }
    }
    __syncthreads();
    // IC epilogue: thread rl = tid>>4, c = tid&15 -> d = c*8..c*8+7
    const int rl = tid >> 4, c = tid & 15, tm = t - 1;
    const int rt = rl >> 4, lr = rl & 15;
    const float m = masks[(size_t)(rB+rl)*128 + tm];
    #pragma unroll
    for (int k=0;k<8;++k){
      const int d = c*8 + k;
      const int djt = d >> 4, cc = d & 15;
      float imp = T_W(rt*8 + djt, lr, cc) + bp[d];
      float xv  = x[((size_t)(rB+rl)*128 + tm)*128 + d];
      float cv  = m*xv + (1.f - m)*imp;
      lds_c[cidx(rt, lr, d)] = f2bf(cv);
      if ((d >> 1) == jj){                       // unique writer: 2 d-cols per jj
        size_t o = ((size_t)(rB+rl)*127 + tm)*128 + d;
        out[131072 + o]  = cv;    // completed
        out[2211840 + o] = imp;   // imputed
      }
    }
  }
  __syncthreads();

  // ---- main L0 matmuls ----
  if (wave < 6){
    // h-part: wave = gg*2 + rt, full K=1024 (2 accumulators), j = jj
    const int gg = wave >> 1, rt = wave & 1;
    v4f a0 = {0.f,0.f,0.f,0.f}, a1 = {0.f,0.f,0.f,0.f};
    const bf16* wp = packL0h + ((size_t)((gg*64 + jj)*32))*512 + lane*8;
    #pragma unroll
    for (int i=0;i<32;i+=2){
      a0 = MFMA(afrag32(lds_h, rt, i,   lane), ldv(wp + (size_t)i*512),     a0);
      a1 = MFMA(afrag32(lds_h, rt, i+1, lane), ldv(wp + (size_t)(i+1)*512), a1);
    }
    const v4f a = a0 + a1;
    #pragma unroll
    for (int r=0;r<4;r++) T_W(wave, quad*4+r, l15) = a[r];
  } else {
    // x-part: wave 6+rt handles gates 0..2, K=128 (4 MFMAs each)
    const int rt = wave - 6;
    #pragma unroll
    for (int gg=0; gg<3; ++gg){
      v4f a = {0.f,0.f,0.f,0.f};
      const bf16* wp = packL0x + ((size_t)((gg*64 + jj)*4))*512 + lane*8;
      #pragma unroll
      for (int i=0;i<4;++i){
        a = MFMA(ldv(lds_c + (size_t)rt*2048 + (size_t)i*512 + lane*8),
                 ldv(wp + (size_t)i*512), a);
      }
      const int slot = 6 + rt*3 + gg;
      #pragma unroll
      for (int r=0;r<4;r++) T_W(slot, quad*4+r, l15) = a[r];
    }
  }
  __syncthreads();
  {
    const int rl = tid >> 4, c = tid & 15;
    const int rt = rl >> 4, lr = rl & 15;
    const int col = jj*16 + c;
    float ghr = T_W(0*2+rt, lr, c);
    float ghz = T_W(1*2+rt, lr, c);
    float ghn = T_W(2*2+rt, lr, c);
    float gir = T_W(6+rt*3+0, lr, c);
    float giz = T_W(6+rt*3+1, lr, c);
    float gin = T_W(6+rt*3+2, lr, c);
    float rgg = sigm(gir + bih0[col]      + ghr + bhh0[col]);
    float zg  = sigm(giz + bih0[1024+col] + ghz + bhh0[1024+col]);
    float nv  = tanh_(gin + bih0[2048+col] + rgg*(ghn + bhh0[2048+col]));
    float hp  = hp32(lds_h, rl, col);
    hB[(size_t)(rB+rl)*1024 + col] = f2bf((1.f - zg)*nv + zg*hp);
  }
}

// =================================================================
// Upper-layer kernel: dst = GRU_lay(src, src)  (input == hidden).
// lay=0: hB->hC, lay=1: hC->hA (+ h_final out at t==127).
// Grid 256 x 512: wave = rt*4 + s (2 row-halves x 4 gates), full K=1024.
// =================================================================
__global__ __launch_bounds__(512) void gru_up(
  const int lay, const int t,
  const float* __restrict__ bihR, const float* __restrict__ bhhR,
  const bf16* __restrict__ packU,
  const bf16* __restrict__ src, bf16* __restrict__ dst,
  float* __restrict__ out)
{
  const int tid  = threadIdx.x;
  const int lane = tid & 63;
  const int wave = tid >> 6;           // 0..7
  const int l15  = lane & 15;
  const int quad = lane >> 4;
  const int bid  = blockIdx.x;
  const int jj   = bid & 63;
  const int rg   = bid >> 6;
  const int rB   = rg * 32;
  const bf16* packL = packU + (size_t)lay*4194304;
  const float* bi = bihR + lay*3072;
  const float* bh = bhhR + lay*3072;
  float* out_h = (lay == 1 && t == 127) ? out : nullptr;

  __shared__ bf16 lds_h[32768];        // 64 KB
  __shared__ float lds2[8*272];

  stage32(src + (size_t)rB*1024, lds_h, wave, lane, l15, quad);
  __syncthreads();
  {
    // wave = rt*4 + s; full K=1024 (2 accumulators); j = jj
    const int rt = wave >> 2, s = wave & 3;
    v4f a0 = {0.f,0.f,0.f,0.f}, a1 = {0.f,0.f,0.f,0.f};
    const bf16* wp = packL + ((size_t)((s*64 + jj)*32))*512 + lane*8;
    #pragma unroll
    for (int i=0;i<32;i+=2){
      a0 = MFMA(afrag32(lds_h, rt, i,   lane), ldv(wp + (size_t)i*512),     a0);
      a1 = MFMA(afrag32(lds_h, rt, i+1, lane), ldv(wp + (size_t)(i+1)*512), a1);
    }
    const v4f a = a0 + a1;
    #pragma unroll
    for (int r=0;r<4;r++) T_W(wave, quad*4+r, l15) = a[r];
  }
  __syncthreads();
  {
    const int rl = tid >> 4, c = tid & 15;
    const int rt = rl >> 4, lr = rl & 15;
    const int col = jj*16 + c;
    float pr  = T_W(rt*4+0, lr, c);
    float pz  = T_W(rt*4+1, lr, c);
    float pin = T_W(rt*4+2, lr, c);
    float phn = T_W(rt*4+3, lr, c);
    float rgg = sigm(pr + bi[col] + bh[col]);
    float zg  = sigm(pz + bi[1024+col] + bh[1024+col]);
    float nv  = tanh_(pin + bi[2048+col] + rgg*(phn + bh[2048+col]));
    float hp  = hp32(lds_h, rl, col);
    float hv  = (1.f - zg)*nv + zg*hp;
    dst[(size_t)(rB+rl)*1024 + col] = f2bf(hv);
    if (out_h) out_h[(size_t)(rB+rl)*1024 + col] = hv;
  }
}

// ---------------- host ----------------
extern "C" void kernel_launch(void* const* d_in, const int* in_sizes, int n_in,
                              void* d_out, int out_size, void* d_ws, size_t ws_size,
                              hipStream_t stream)
{
  (void)in_sizes; (void)n_in; (void)out_size; (void)ws_size;
  const float* x     = (const float*)d_in[0];
  const float* masks = (const float*)d_in[1];
  const float* Wih0  = (const float*)d_in[2];
  const float* Whh0  = (const float*)d_in[3];
  const float* bih0  = (const float*)d_in[4];
  const float* bhh0  = (const float*)d_in[5];
  const float* WihR  = (const float*)d_in[6];
  const float* WhhR  = (const float*)d_in[7];
  const float* bihR  = (const float*)d_in[8];
  const float* bhhR  = (const float*)d_in[9];
  const float* Wp    = (const float*)d_in[10];
  const float* bp    = (const float*)d_in[11];
  float* out = (float*)d_out;

  // ws: pad 4096B | hA hB hC (bf16 131072 ea) | packed weights
  bf16* hA      = (bf16*)((char*)d_ws + 4096);
  bf16* hB      = hA + 131072;
  bf16* hC      = hB + 131072;
  bf16* packU   = hC + 131072;         // 8,388,608 elems
  bf16* packL0h = packU + 8388608;     // 3,145,728
  bf16* packL0x = packL0h + 3145728;   // 393,216
  bf16* packImp = packL0x + 393216;    // 131,072

  hipLaunchKernelGGL(init_pk,      dim3(512),  dim3(256), 0, stream, hA);
  hipLaunchKernelGGL(pack_upper_k, dim3(4096), dim3(256), 0, stream, WihR, WhhR, packU);
  hipLaunchKernelGGL(pack_l0h_k,   dim3(1536), dim3(256), 0, stream, Whh0, packL0h);
  hipLaunchKernelGGL(pack_l0x_k,   dim3(192),  dim3(256), 0, stream, Wih0, packL0x);
  hipLaunchKernelGGL(pack_imp_k,   dim3(64),   dim3(256), 0, stream, Wp, packImp);

  for (int t = 0; t < 128; ++t){
    hipLaunchKernelGGL(gru_l0, dim3(256), dim3(512), 0, stream,
        t, x, masks, bih0, bhh0, bp, packL0h, packL0x, packImp, hA, hB, out);
    hipLaunchKernelGGL(gru_up, dim3(256), dim3(512), 0, stream,
        0, t, bihR, bhhR, packU, hB, hC, out);
    hipLaunchKernelGGL(gru_up, dim3(256), dim3(512), 0, stream,
        1, t, bihR, bhhR, packU, hC, hA, out);
  }
}

// Round 11
// 3149.444 us; speedup vs baseline: 1.2560x; 1.2560x over previous
//
#include <hip/hip_runtime.h>
#include <hip/hip_bf16.h>

// GRU-imputation scan (B=128,T=128,D=128,H=1024,L=3), f32 in/out.
// Round 13: gru_l0 reverted to the exact R11 version (2983 us verified).
// gru_up rebuilt at G=4 row-groups (32 rows x 16 cols per block) with
// IN-REGISTER weight reuse: wave = (gate s, K-half kh); each weight fragment
// is loaded once and feeds MFMAs for BOTH row-halves (rt=0,1) -> issued
// weight bytes/block 256->128 KB (R12 failed because both rt waves re-read
// the same tiles). K-split partials summed in epilogue (validated pattern).

typedef __hip_bfloat16 bf16;
typedef unsigned int u32;
typedef unsigned short u16;
typedef __attribute__((ext_vector_type(8))) short v8bf;   // 8 x bf16 (16B)
typedef __attribute__((ext_vector_type(4))) float v4f;    // MFMA C/D
typedef __attribute__((ext_vector_type(4))) u32 v4u;

__device__ __forceinline__ float bf2f(bf16 v){ return __bfloat162float(v); }
__device__ __forceinline__ bf16 f2bf(float v){ return __float2bfloat16(v); }
__device__ __forceinline__ float sigm(float x){ return 1.f/(1.f + __expf(-x)); }
__device__ __forceinline__ float tanh_(float x){
  float a = fminf(fmaxf(x, -15.f), 15.f);
  float t = __expf(2.f*a);
  return (t-1.f)/(t+1.f);
}
__device__ __forceinline__ v8bf ldv(const bf16* p){ return *reinterpret_cast<const v8bf*>(p); }

// =================================================================
// Packing kernels (unchanged; validated).
// Fragment unit = 64 lanes x 8 bf16; lane's 8 elems =
//   W[row(j,lane&15)][kk*32 + ((lane>>4)&3)*8 + e]
// =================================================================
__global__ void pack_upper_k(const float* __restrict__ Wih, const float* __restrict__ Whh,
                             bf16* __restrict__ dst){
  int tid = blockIdx.x*256 + threadIdx.x;          // 1,048,576
  int lane = tid & 63;
  int u    = tid >> 6;
  int kk   = u & 31;
  int j    = (u >> 5) & 63;
  int s    = (u >> 11) & 3;
  int l    = u >> 13;
  int n    = j*16 + (lane & 15);
  int k    = kk*32 + ((lane>>4)&3)*8;
  int row  = (s==0) ? n : (s==1 ? 1024+n : 2048+n);
  size_t src = ((size_t)l*3072 + row)*1024 + k;
  size_t o = (size_t)tid*8;
  #pragma unroll
  for (int e=0;e<8;e++){
    float v;
    if (s < 2)      v = Wih[src+e] + Whh[src+e];
    else if (s==2)  v = Wih[src+e];
    else            v = Whh[src+e];
    dst[o+e] = f2bf(v);
  }
}
__global__ void pack_l0h_k(const float* __restrict__ Whh0, bf16* __restrict__ dst){
  int tid = blockIdx.x*256 + threadIdx.x;          // 393,216
  int lane = tid & 63;
  int u  = tid >> 6;
  int kk = u & 31;
  int j  = (u >> 5) & 63;
  int g  = u >> 11;
  int row = g*1024 + j*16 + (lane&15);
  int k   = kk*32 + ((lane>>4)&3)*8;
  size_t src = (size_t)row*1024 + k;
  size_t o = (size_t)tid*8;
  #pragma unroll
  for (int e=0;e<8;e++) dst[o+e] = f2bf(Whh0[src+e]);
}
__global__ void pack_l0x_k(const float* __restrict__ Wih0, bf16* __restrict__ dst){
  int tid = blockIdx.x*256 + threadIdx.x;          // 49,152
  int lane = tid & 63;
  int u  = tid >> 6;
  int kk = u & 3;
  int j  = (u >> 2) & 63;
  int g  = u >> 8;
  int row = g*1024 + j*16 + (lane&15);
  int k   = kk*32 + ((lane>>4)&3)*8;
  size_t src = (size_t)row*128 + k;
  size_t o = (size_t)tid*8;
  #pragma unroll
  for (int e=0;e<8;e++) dst[o+e] = f2bf(Wih0[src+e]);
}
__global__ void pack_imp_k(const float* __restrict__ Wp, bf16* __restrict__ dst){
  int tid = blockIdx.x*256 + threadIdx.x;          // 16,384
  int lane = tid & 63;
  int u  = tid >> 6;
  int kk = u & 31;
  int jj = u >> 5;
  int row = jj*16 + (lane&15);
  int k   = kk*32 + ((lane>>4)&3)*8;
  size_t src = (size_t)row*1024 + k;
  size_t o = (size_t)tid*8;
  #pragma unroll
  for (int e=0;e<8;e++) dst[o+e] = f2bf(Wp[src+e]);
}
__global__ void init_pk(bf16* __restrict__ hA){
  int tid = blockIdx.x*256 + threadIdx.x;          // 131,072
  hA[tid] = f2bf(0.f);                             // h0 = 0
}

// =================================================================
// 16-row fragment layout (R11, validated): lds_h16[kk*512 + lane*8] =
//   h[lane&15][kk*32 + (lane>>4)*8 + e]
// =================================================================
__device__ __forceinline__ v8bf afrag(const bf16* lds_h, int kk, int lane){
  return ldv(lds_h + (size_t)kk*512 + (size_t)lane*8);
}
__device__ __forceinline__ float hp16(const bf16* lds_h, int rl, int colh){
  int kk = colh >> 5, q = (colh >> 3) & 3, e = colh & 7;
  return bf2f(lds_h[(size_t)kk*512 + (size_t)(q*16 + rl)*8 + e]);
}
// 32-row layout (R12, validated): two 16-row halves rt=0,1.
__device__ __forceinline__ v8bf afrag32(const bf16* lds_h, int rt, int kk, int lane){
  return ldv(lds_h + (size_t)rt*16384 + (size_t)kk*512 + (size_t)lane*8);
}
__device__ __forceinline__ float hp32(const bf16* lds_h, int rl, int colh){
  int rt = rl >> 4, lr = rl & 15;
  int kk = colh >> 5, q = (colh >> 3) & 3, e = colh & 7;
  return bf2f(lds_h[(size_t)rt*16384 + (size_t)kk*512 + (size_t)(q*16 + lr)*8 + e]);
}

#define MFMA(a,b,c) __builtin_amdgcn_mfma_f32_16x16x32_bf16((a),(b),(c),0,0,0)

// lds2 tile: 16x16 f32 at stride 17 (pad), tile stride 272
#define T_W(w, row, col)  lds2[(w)*272 + (row)*17 + (col)]

// stage 16 rows x 1024 cols of h -> fragment LDS; 8 waves, wave w stages
// kk = 4w..4w+3 (plain cached loads). (R11, validated)
__device__ __forceinline__ void stage16_8(const bf16* __restrict__ src_rg, bf16* lds_h,
                                          int wave, int lane, int l15, int quad){
  const bf16* g0 = src_rg + (size_t)l15*1024 + wave*128 + quad*8;
  v4u r0 = *(const v4u*)(g0);
  v4u r1 = *(const v4u*)(g0 + 32);
  v4u r2 = *(const v4u*)(g0 + 64);
  v4u r3 = *(const v4u*)(g0 + 96);
  bf16* d = lds_h + (size_t)(wave*4)*512 + (size_t)lane*8;
  *(v4u*)(d)        = r0;
  *(v4u*)(d + 512)  = r1;
  *(v4u*)(d + 1024) = r2;
  *(v4u*)(d + 1536) = r3;
}
// stage 32 rows: rt = w>>2, kq = w&3 -> units kk = kq*8..kq*8+7 of half rt.
// (R12, validated indexing)
__device__ __forceinline__ void stage32(const bf16* __restrict__ src_rg, bf16* lds_h,
                                        int wave, int lane, int l15, int quad){
  const int rt = wave >> 2, kq = wave & 3;
  const bf16* g0 = src_rg + (size_t)(rt*16 + l15)*1024 + kq*256 + quad*8;
  bf16* d0 = lds_h + (size_t)rt*16384 + (size_t)(kq*8)*512 + (size_t)lane*8;
  #pragma unroll
  for (int i=0;i<8;++i){
    v4u r = *(const v4u*)(g0 + i*32);
    *(v4u*)(d0 + i*512) = r;
  }
}

// =================================================================
// L0 kernel — EXACT R11 version (verified at 2983 us).
// Grid 256 x 512: cseg = bid&31 (32 cols, cseg%8 = XCD), g = bid>>5 (16 rows).
// =================================================================
__global__ __launch_bounds__(512) void gru_l0(
  const int t,
  const float* __restrict__ x, const float* __restrict__ masks,
  const float* __restrict__ bih0, const float* __restrict__ bhh0,
  const float* __restrict__ bp,
  const bf16* __restrict__ packL0h, const bf16* __restrict__ packL0x,
  const bf16* __restrict__ packImp,
  const bf16* __restrict__ hA, bf16* __restrict__ hB,
  float* __restrict__ out)
{
  const int tid  = threadIdx.x;
  const int lane = tid & 63;
  const int wave = tid >> 6;           // 0..7
  const int l15  = lane & 15;
  const int quad = lane >> 4;
  const int bid  = blockIdx.x;
  const int cseg = bid & 31;
  const int g    = bid >> 5;
  const int rB   = g * 16;

  __shared__ bf16 lds_h[16384];        // 32 KB staged h slice
  __shared__ bf16 lds_c[2048];         // 4 KB staged comp slice
  __shared__ float lds2[12*272];       // ~12.8 KB partial tiles (padded)

  stage16_8(hA + (size_t)rB*1024, lds_h, wave, lane, l15, quad);
  __syncthreads();

  // ---- fused IC: build comp(t-1) slice into lds_c; write out for t>=1 ----
  if (t == 0){
    const int rl = tid >> 5, cb = tid & 31;
    #pragma unroll
    for (int k=0;k<4;++k){
      const int d = cb*4 + k;
      float v = x[(size_t)(rB+rl)*16384 + d];
      lds_c[(size_t)(d>>5)*512 + (size_t)(((d>>3)&3)*16 + rl)*8 + (d&7)] = f2bf(v);
    }
  } else {
    {
      const int jt = wave;
      v4f a0 = {0.f,0.f,0.f,0.f}, a1 = {0.f,0.f,0.f,0.f};
      const bf16* wp = packImp + ((size_t)(jt*32))*512 + lane*8;
      #pragma unroll
      for (int i=0;i<32;i+=2){
        a0 = MFMA(afrag(lds_h, i,   lane), ldv(wp + (size_t)i*512),     a0);
        a1 = MFMA(afrag(lds_h, i+1, lane), ldv(wp + (size_t)(i+1)*512), a1);
      }
      const v4f a = a0 + a1;
      #pragma unroll
      for (int r=0;r<4;r++) T_W(jt, quad*4+r, l15) = a[r];
    }
    __syncthreads();
    const int rl = tid >> 5, cb = tid & 31, tm = t - 1;
    const float m = masks[(size_t)(rB+rl)*128 + tm];
    const bool wr = (cb == cseg);                 // unique writer per 4 cols
    #pragma unroll
    for (int k=0;k<4;++k){
      const int d = cb*4 + k;
      const int djt = d >> 4, c = d & 15;
      float imp = T_W(djt, rl, c) + bp[d];
      float xv  = x[((size_t)(rB+rl)*128 + tm)*128 + d];
      float cv  = m*xv + (1.f - m)*imp;
      lds_c[(size_t)(d>>5)*512 + (size_t)(((d>>3)&3)*16 + rl)*8 + (d&7)] = f2bf(cv);
      if (wr){
        size_t o = ((size_t)(rB+rl)*127 + tm)*128 + d;
        out[131072 + o]  = cv;    // completed
        out[2211840 + o] = imp;   // imputed
      }
    }
  }
  __syncthreads();

  // ---- main L0 matmuls ----
  if (wave < 6){
    const int gg = wave >> 1, jt = wave & 1;
    const int j = cseg*2 + jt;
    v4f a0 = {0.f,0.f,0.f,0.f}, a1 = {0.f,0.f,0.f,0.f};
    const bf16* wp = packL0h + ((size_t)((gg*64 + j)*32))*512 + lane*8;
    #pragma unroll
    for (int i=0;i<32;i+=2){
      a0 = MFMA(afrag(lds_h, i,   lane), ldv(wp + (size_t)i*512),     a0);
      a1 = MFMA(afrag(lds_h, i+1, lane), ldv(wp + (size_t)(i+1)*512), a1);
    }
    const v4f a = a0 + a1;
    #pragma unroll
    for (int r=0;r<4;r++) T_W(wave, quad*4+r, l15) = a[r];
  } else {
    const int jt = wave - 6;
    const int j = cseg*2 + jt;
    #pragma unroll
    for (int gg=0; gg<3; ++gg){
      v4f a = {0.f,0.f,0.f,0.f};
      const bf16* wp = packL0x + ((size_t)((gg*64 + j)*4))*512 + lane*8;
      #pragma unroll
      for (int i=0;i<4;++i){
        a = MFMA(ldv(lds_c + (size_t)i*512 + lane*8), ldv(wp + (size_t)i*512), a);
      }
      const int slot = 6 + gg*2 + jt;
      #pragma unroll
      for (int r=0;r<4;r++) T_W(slot, quad*4+r, l15) = a[r];
    }
  }
  __syncthreads();
  {
    const int rl = tid >> 5, cb = tid & 31;
    const int jt = cb >> 4, c = cb & 15;
    const int col = cseg*32 + cb;
    float ghr = T_W(0*2+jt, rl, c);
    float ghz = T_W(1*2+jt, rl, c);
    float ghn = T_W(2*2+jt, rl, c);
    float gir = T_W(6+0*2+jt, rl, c);
    float giz = T_W(6+1*2+jt, rl, c);
    float gin = T_W(6+2*2+jt, rl, c);
    float rgg = sigm(gir + bih0[col]      + ghr + bhh0[col]);
    float zg  = sigm(giz + bih0[1024+col] + ghz + bhh0[1024+col]);
    float nv  = tanh_(gin + bih0[2048+col] + rgg*(ghn + bhh0[2048+col]));
    float hp  = hp16(lds_h, rl, col);
    hB[(size_t)(rB+rl)*1024 + col] = f2bf((1.f - zg)*nv + zg*hp);
  }
}

// =================================================================
// Upper-layer kernel — G=4 with in-register weight reuse.
// Grid 256 x 512: jj = bid&63 (16 cols, jj%8 = XCD), rg = bid>>6 (32 rows).
// Wave = (gate s = w>>1, K-half kh = w&1): 16 K-units; each weight fragment
// loaded ONCE, consumed by 2 MFMAs (rt=0,1). K-split summed in epilogue.
// =================================================================
__global__ __launch_bounds__(512) void gru_up(
  const int lay, const int t,
  const float* __restrict__ bihR, const float* __restrict__ bhhR,
  const bf16* __restrict__ packU,
  const bf16* __restrict__ src, bf16* __restrict__ dst,
  float* __restrict__ out)
{
  const int tid  = threadIdx.x;
  const int lane = tid & 63;
  const int wave = tid >> 6;           // 0..7
  const int l15  = lane & 15;
  const int quad = lane >> 4;
  const int bid  = blockIdx.x;
  const int jj   = bid & 63;
  const int rg   = bid >> 6;
  const int rB   = rg * 32;
  const bf16* packL = packU + (size_t)lay*4194304;
  const float* bi = bihR + lay*3072;
  const float* bh = bhhR + lay*3072;
  float* out_h = (lay == 1 && t == 127) ? out : nullptr;

  __shared__ bf16 lds_h[32768];        // 64 KB staged h slice (32 x 1024)
  __shared__ float lds2[16*272];       // ~17.4 KB partials (padded)

  stage32(src + (size_t)rB*1024, lds_h, wave, lane, l15, quad);
  __syncthreads();
  {
    // wave = s*2 + kh; 16 K-units, weight loaded once, 2 MFMAs per unit.
    const int s = wave >> 1, kh = wave & 1;
    v4f a0 = {0.f,0.f,0.f,0.f}, a1 = {0.f,0.f,0.f,0.f};
    const bf16* wp = packL + ((size_t)((s*64 + jj)*32 + kh*16))*512 + lane*8;
    #pragma unroll
    for (int i=0;i<16;++i){
      const int kk = kh*16 + i;
      v8bf wf = ldv(wp + (size_t)i*512);
      a0 = MFMA(afrag32(lds_h, 0, kk, lane), wf, a0);
      a1 = MFMA(afrag32(lds_h, 1, kk, lane), wf, a1);
    }
    // slot = kh*8 + s*2 + rt
    #pragma unroll
    for (int r=0;r<4;r++){
      T_W(kh*8 + s*2 + 0, quad*4+r, l15) = a0[r];
      T_W(kh*8 + s*2 + 1, quad*4+r, l15) = a1[r];
    }
  }
  __syncthreads();
  {
    const int rl = tid >> 4, c = tid & 15;      // 32 rows x 16 cols
    const int rt = rl >> 4, lr = rl & 15;
    const int col = jj*16 + c;
    float pr  = T_W(0*2+rt, lr, c) + T_W(8+0*2+rt, lr, c);
    float pz  = T_W(1*2+rt, lr, c) + T_W(8+1*2+rt, lr, c);
    float pin = T_W(2*2+rt, lr, c) + T_W(8+2*2+rt, lr, c);
    float phn = T_W(3*2+rt, lr, c) + T_W(8+3*2+rt, lr, c);
    float rgg = sigm(pr + bi[col] + bh[col]);
    float zg  = sigm(pz + bi[1024+col] + bh[1024+col]);
    float nv  = tanh_(pin + bi[2048+col] + rgg*(phn + bh[2048+col]));
    float hp  = hp32(lds_h, rl, col);
    float hv  = (1.f - zg)*nv + zg*hp;
    dst[(size_t)(rB+rl)*1024 + col] = f2bf(hv);
    if (out_h) out_h[(size_t)(rB+rl)*1024 + col] = hv;
  }
}

// ---------------- host ----------------
extern "C" void kernel_launch(void* const* d_in, const int* in_sizes, int n_in,
                              void* d_out, int out_size, void* d_ws, size_t ws_size,
                              hipStream_t stream)
{
  (void)in_sizes; (void)n_in; (void)out_size; (void)ws_size;
  const float* x     = (const float*)d_in[0];
  const float* masks = (const float*)d_in[1];
  const float* Wih0  = (const float*)d_in[2];
  const float* Whh0  = (const float*)d_in[3];
  const float* bih0  = (const float*)d_in[4];
  const float* bhh0  = (const float*)d_in[5];
  const float* WihR  = (const float*)d_in[6];
  const float* WhhR  = (const float*)d_in[7];
  const float* bihR  = (const float*)d_in[8];
  const float* bhhR  = (const float*)d_in[9];
  const float* Wp    = (const float*)d_in[10];
  const float* bp    = (const float*)d_in[11];
  float* out = (float*)d_out;

  // ws: pad 4096B | hA hB hC (bf16 131072 ea) | packed weights
  bf16* hA      = (bf16*)((char*)d_ws + 4096);
  bf16* hB      = hA + 131072;
  bf16* hC      = hB + 131072;
  bf16* packU   = hC + 131072;         // 8,388,608 elems
  bf16* packL0h = packU + 8388608;     // 3,145,728
  bf16* packL0x = packL0h + 3145728;   // 393,216
  bf16* packImp = packL0x + 393216;    // 131,072

  hipLaunchKernelGGL(init_pk,      dim3(512),  dim3(256), 0, stream, hA);
  hipLaunchKernelGGL(pack_upper_k, dim3(4096), dim3(256), 0, stream, WihR, WhhR, packU);
  hipLaunchKernelGGL(pack_l0h_k,   dim3(1536), dim3(256), 0, stream, Whh0, packL0h);
  hipLaunchKernelGGL(pack_l0x_k,   dim3(192),  dim3(256), 0, stream, Wih0, packL0x);
  hipLaunchKernelGGL(pack_imp_k,   dim3(64),   dim3(256), 0, stream, Wp, packImp);

  for (int t = 0; t < 128; ++t){
    hipLaunchKernelGGL(gru_l0, dim3(256), dim3(512), 0, stream,
        t, x, masks, bih0, bhh0, bp, packL0h, packL0x, packImp, hA, hB, out);
    hipLaunchKernelGGL(gru_up, dim3(256), dim3(512), 0, stream,
        0, t, bihR, bhhR, packU, hB, hC, out);
    hipLaunchKernelGGL(gru_up, dim3(256), dim3(512), 0, stream,
        1, t, bihR, bhhR, packU, hC, hA, out);
  }
}

// Round 12
// 2875.824 us; speedup vs baseline: 1.3755x; 1.0951x over previous
//
#include <hip/hip_runtime.h>
#include <hip/hip_bf16.h>

// GRU-imputation scan (B=128,T=128,D=128,H=1024,L=3), f32 in/out.
// Round 14: gru_l0 = EXACT R11 (verified 2983 us). gru_up = R11 + software-
// pipelined weight prefetch: stage loads issued first, then 8 weight
// fragments into VGPRs (latency hides under stage+syncthreads; issue order
// keeps ds_write's in-order vmcnt off the weight loads), then 4x8 ping-pong
// prefetch through the 32-MFMA loop. Clean A/B vs R11: only gru_up changed.

typedef __hip_bfloat16 bf16;
typedef unsigned int u32;
typedef unsigned short u16;
typedef __attribute__((ext_vector_type(8))) short v8bf;   // 8 x bf16 (16B)
typedef __attribute__((ext_vector_type(4))) float v4f;    // MFMA C/D
typedef __attribute__((ext_vector_type(4))) u32 v4u;

__device__ __forceinline__ float bf2f(bf16 v){ return __bfloat162float(v); }
__device__ __forceinline__ bf16 f2bf(float v){ return __float2bfloat16(v); }
__device__ __forceinline__ float sigm(float x){ return 1.f/(1.f + __expf(-x)); }
__device__ __forceinline__ float tanh_(float x){
  float a = fminf(fmaxf(x, -15.f), 15.f);
  float t = __expf(2.f*a);
  return (t-1.f)/(t+1.f);
}
__device__ __forceinline__ v8bf ldv(const bf16* p){ return *reinterpret_cast<const v8bf*>(p); }

// =================================================================
// Packing kernels (unchanged; validated).
// Fragment unit = 64 lanes x 8 bf16; lane's 8 elems =
//   W[row(j,lane&15)][kk*32 + ((lane>>4)&3)*8 + e]
// =================================================================
__global__ void pack_upper_k(const float* __restrict__ Wih, const float* __restrict__ Whh,
                             bf16* __restrict__ dst){
  int tid = blockIdx.x*256 + threadIdx.x;          // 1,048,576
  int lane = tid & 63;
  int u    = tid >> 6;
  int kk   = u & 31;
  int j    = (u >> 5) & 63;
  int s    = (u >> 11) & 3;
  int l    = u >> 13;
  int n    = j*16 + (lane & 15);
  int k    = kk*32 + ((lane>>4)&3)*8;
  int row  = (s==0) ? n : (s==1 ? 1024+n : 2048+n);
  size_t src = ((size_t)l*3072 + row)*1024 + k;
  size_t o = (size_t)tid*8;
  #pragma unroll
  for (int e=0;e<8;e++){
    float v;
    if (s < 2)      v = Wih[src+e] + Whh[src+e];
    else if (s==2)  v = Wih[src+e];
    else            v = Whh[src+e];
    dst[o+e] = f2bf(v);
  }
}
__global__ void pack_l0h_k(const float* __restrict__ Whh0, bf16* __restrict__ dst){
  int tid = blockIdx.x*256 + threadIdx.x;          // 393,216
  int lane = tid & 63;
  int u  = tid >> 6;
  int kk = u & 31;
  int j  = (u >> 5) & 63;
  int g  = u >> 11;
  int row = g*1024 + j*16 + (lane&15);
  int k   = kk*32 + ((lane>>4)&3)*8;
  size_t src = (size_t)row*1024 + k;
  size_t o = (size_t)tid*8;
  #pragma unroll
  for (int e=0;e<8;e++) dst[o+e] = f2bf(Whh0[src+e]);
}
__global__ void pack_l0x_k(const float* __restrict__ Wih0, bf16* __restrict__ dst){
  int tid = blockIdx.x*256 + threadIdx.x;          // 49,152
  int lane = tid & 63;
  int u  = tid >> 6;
  int kk = u & 3;
  int j  = (u >> 2) & 63;
  int g  = u >> 8;
  int row = g*1024 + j*16 + (lane&15);
  int k   = kk*32 + ((lane>>4)&3)*8;
  size_t src = (size_t)row*128 + k;
  size_t o = (size_t)tid*8;
  #pragma unroll
  for (int e=0;e<8;e++) dst[o+e] = f2bf(Wih0[src+e]);
}
__global__ void pack_imp_k(const float* __restrict__ Wp, bf16* __restrict__ dst){
  int tid = blockIdx.x*256 + threadIdx.x;          // 16,384
  int lane = tid & 63;
  int u  = tid >> 6;
  int kk = u & 31;
  int jj = u >> 5;
  int row = jj*16 + (lane&15);
  int k   = kk*32 + ((lane>>4)&3)*8;
  size_t src = (size_t)row*1024 + k;
  size_t o = (size_t)tid*8;
  #pragma unroll
  for (int e=0;e<8;e++) dst[o+e] = f2bf(Wp[src+e]);
}
__global__ void init_pk(bf16* __restrict__ hA){
  int tid = blockIdx.x*256 + threadIdx.x;          // 131,072
  hA[tid] = f2bf(0.f);                             // h0 = 0
}

// =================================================================
// 16-row fragment layout (R11, validated): lds_h[kk*512 + lane*8] =
//   h[lane&15][kk*32 + (lane>>4)*8 + e]
// =================================================================
__device__ __forceinline__ v8bf afrag(const bf16* lds_h, int kk, int lane){
  return ldv(lds_h + (size_t)kk*512 + (size_t)lane*8);
}
__device__ __forceinline__ float hp16(const bf16* lds_h, int rl, int colh){
  int kk = colh >> 5, q = (colh >> 3) & 3, e = colh & 7;
  return bf2f(lds_h[(size_t)kk*512 + (size_t)(q*16 + rl)*8 + e]);
}

#define MFMA(a,b,c) __builtin_amdgcn_mfma_f32_16x16x32_bf16((a),(b),(c),0,0,0)

// lds2 tile: 16x16 f32 at stride 17 (pad), tile stride 272
#define T_W(w, row, col)  lds2[(w)*272 + (row)*17 + (col)]

// stage 16 rows x 1024 cols of h -> fragment LDS; 8 waves, wave w stages
// kk = 4w..4w+3 (plain cached loads). (R11, validated)
__device__ __forceinline__ void stage16_8(const bf16* __restrict__ src_rg, bf16* lds_h,
                                          int wave, int lane, int l15, int quad){
  const bf16* g0 = src_rg + (size_t)l15*1024 + wave*128 + quad*8;
  v4u r0 = *(const v4u*)(g0);
  v4u r1 = *(const v4u*)(g0 + 32);
  v4u r2 = *(const v4u*)(g0 + 64);
  v4u r3 = *(const v4u*)(g0 + 96);
  bf16* d = lds_h + (size_t)(wave*4)*512 + (size_t)lane*8;
  *(v4u*)(d)        = r0;
  *(v4u*)(d + 512)  = r1;
  *(v4u*)(d + 1024) = r2;
  *(v4u*)(d + 1536) = r3;
}

// =================================================================
// L0 kernel — EXACT R11 version (verified at 2983 us).
// Grid 256 x 512: cseg = bid&31 (32 cols, cseg%8 = XCD), g = bid>>5 (16 rows).
// =================================================================
__global__ __launch_bounds__(512) void gru_l0(
  const int t,
  const float* __restrict__ x, const float* __restrict__ masks,
  const float* __restrict__ bih0, const float* __restrict__ bhh0,
  const float* __restrict__ bp,
  const bf16* __restrict__ packL0h, const bf16* __restrict__ packL0x,
  const bf16* __restrict__ packImp,
  const bf16* __restrict__ hA, bf16* __restrict__ hB,
  float* __restrict__ out)
{
  const int tid  = threadIdx.x;
  const int lane = tid & 63;
  const int wave = tid >> 6;           // 0..7
  const int l15  = lane & 15;
  const int quad = lane >> 4;
  const int bid  = blockIdx.x;
  const int cseg = bid & 31;
  const int g    = bid >> 5;
  const int rB   = g * 16;

  __shared__ bf16 lds_h[16384];        // 32 KB staged h slice
  __shared__ bf16 lds_c[2048];         // 4 KB staged comp slice
  __shared__ float lds2[12*272];       // ~12.8 KB partial tiles (padded)

  stage16_8(hA + (size_t)rB*1024, lds_h, wave, lane, l15, quad);
  __syncthreads();

  // ---- fused IC: build comp(t-1) slice into lds_c; write out for t>=1 ----
  if (t == 0){
    const int rl = tid >> 5, cb = tid & 31;
    #pragma unroll
    for (int k=0;k<4;++k){
      const int d = cb*4 + k;
      float v = x[(size_t)(rB+rl)*16384 + d];
      lds_c[(size_t)(d>>5)*512 + (size_t)(((d>>3)&3)*16 + rl)*8 + (d&7)] = f2bf(v);
    }
  } else {
    {
      const int jt = wave;
      v4f a0 = {0.f,0.f,0.f,0.f}, a1 = {0.f,0.f,0.f,0.f};
      const bf16* wp = packImp + ((size_t)(jt*32))*512 + lane*8;
      #pragma unroll
      for (int i=0;i<32;i+=2){
        a0 = MFMA(afrag(lds_h, i,   lane), ldv(wp + (size_t)i*512),     a0);
        a1 = MFMA(afrag(lds_h, i+1, lane), ldv(wp + (size_t)(i+1)*512), a1);
      }
      const v4f a = a0 + a1;
      #pragma unroll
      for (int r=0;r<4;r++) T_W(jt, quad*4+r, l15) = a[r];
    }
    __syncthreads();
    const int rl = tid >> 5, cb = tid & 31, tm = t - 1;
    const float m = masks[(size_t)(rB+rl)*128 + tm];
    const bool wr = (cb == cseg);                 // unique writer per 4 cols
    #pragma unroll
    for (int k=0;k<4;++k){
      const int d = cb*4 + k;
      const int djt = d >> 4, c = d & 15;
      float imp = T_W(djt, rl, c) + bp[d];
      float xv  = x[((size_t)(rB+rl)*128 + tm)*128 + d];
      float cv  = m*xv + (1.f - m)*imp;
      lds_c[(size_t)(d>>5)*512 + (size_t)(((d>>3)&3)*16 + rl)*8 + (d&7)] = f2bf(cv);
      if (wr){
        size_t o = ((size_t)(rB+rl)*127 + tm)*128 + d;
        out[131072 + o]  = cv;    // completed
        out[2211840 + o] = imp;   // imputed
      }
    }
  }
  __syncthreads();

  // ---- main L0 matmuls ----
  if (wave < 6){
    const int gg = wave >> 1, jt = wave & 1;
    const int j = cseg*2 + jt;
    v4f a0 = {0.f,0.f,0.f,0.f}, a1 = {0.f,0.f,0.f,0.f};
    const bf16* wp = packL0h + ((size_t)((gg*64 + j)*32))*512 + lane*8;
    #pragma unroll
    for (int i=0;i<32;i+=2){
      a0 = MFMA(afrag(lds_h, i,   lane), ldv(wp + (size_t)i*512),     a0);
      a1 = MFMA(afrag(lds_h, i+1, lane), ldv(wp + (size_t)(i+1)*512), a1);
    }
    const v4f a = a0 + a1;
    #pragma unroll
    for (int r=0;r<4;r++) T_W(wave, quad*4+r, l15) = a[r];
  } else {
    const int jt = wave - 6;
    const int j = cseg*2 + jt;
    #pragma unroll
    for (int gg=0; gg<3; ++gg){
      v4f a = {0.f,0.f,0.f,0.f};
      const bf16* wp = packL0x + ((size_t)((gg*64 + j)*4))*512 + lane*8;
      #pragma unroll
      for (int i=0;i<4;++i){
        a = MFMA(ldv(lds_c + (size_t)i*512 + lane*8), ldv(wp + (size_t)i*512), a);
      }
      const int slot = 6 + gg*2 + jt;
      #pragma unroll
      for (int r=0;r<4;r++) T_W(slot, quad*4+r, l15) = a[r];
    }
  }
  __syncthreads();
  {
    const int rl = tid >> 5, cb = tid & 31;
    const int jt = cb >> 4, c = cb & 15;
    const int col = cseg*32 + cb;
    float ghr = T_W(0*2+jt, rl, c);
    float ghz = T_W(1*2+jt, rl, c);
    float ghn = T_W(2*2+jt, rl, c);
    float gir = T_W(6+0*2+jt, rl, c);
    float giz = T_W(6+1*2+jt, rl, c);
    float gin = T_W(6+2*2+jt, rl, c);
    float rgg = sigm(gir + bih0[col]      + ghr + bhh0[col]);
    float zg  = sigm(giz + bih0[1024+col] + ghz + bhh0[1024+col]);
    float nv  = tanh_(gin + bih0[2048+col] + rgg*(ghn + bhh0[2048+col]));
    float hp  = hp16(lds_h, rl, col);
    hB[(size_t)(rB+rl)*1024 + col] = f2bf((1.f - zg)*nv + zg*hp);
  }
}

// =================================================================
// Upper-layer kernel — R11 structure + software-pipelined weight prefetch.
// Grid 256 x 512: cseg = bid&31, g = bid>>5. Wave = (s = w>>1, jt = w&1),
// j = cseg*2 + jt, full K=1024.
// Issue order: stage loads -> weight prefetch (8) -> ds_writes -> sync ->
// 4x8 MFMA blocks with next-8 prefetch.
// =================================================================
__global__ __launch_bounds__(512) void gru_up(
  const int lay, const int t,
  const float* __restrict__ bihR, const float* __restrict__ bhhR,
  const bf16* __restrict__ packU,
  const bf16* __restrict__ src, bf16* __restrict__ dst,
  float* __restrict__ out)
{
  const int tid  = threadIdx.x;
  const int lane = tid & 63;
  const int wave = tid >> 6;           // 0..7
  const int l15  = lane & 15;
  const int quad = lane >> 4;
  const int bid  = blockIdx.x;
  const int cseg = bid & 31;
  const int g    = bid >> 5;
  const int rB   = g * 16;
  const bf16* packL = packU + (size_t)lay*4194304;
  const float* bi = bihR + lay*3072;
  const float* bh = bhhR + lay*3072;
  float* out_h = (lay == 1 && t == 127) ? out : nullptr;

  __shared__ bf16 lds_h[16384];
  __shared__ float lds2[8*272];

  // ---- stage loads first (in-order vmcnt: ds_write waits only on these) ----
  const bf16* g0 = src + (size_t)(rB + l15)*1024 + wave*128 + quad*8;
  v4u r0 = *(const v4u*)(g0);
  v4u r1 = *(const v4u*)(g0 + 32);
  v4u r2 = *(const v4u*)(g0 + 64);
  v4u r3 = *(const v4u*)(g0 + 96);

  // ---- weight prefetch: first 8 fragments into VGPRs ----
  const int s = wave >> 1, jt = wave & 1;
  const int j = cseg*2 + jt;
  const bf16* wp = packL + ((size_t)((s*64 + j)*32))*512 + lane*8;
  v8bf w[8];
  #pragma unroll
  for (int i=0;i<8;++i) w[i] = ldv(wp + (size_t)i*512);

  // ---- LDS writes + sync ----
  {
    bf16* d = lds_h + (size_t)(wave*4)*512 + (size_t)lane*8;
    *(v4u*)(d)        = r0;
    *(v4u*)(d + 512)  = r1;
    *(v4u*)(d + 1024) = r2;
    *(v4u*)(d + 1536) = r3;
  }
  __syncthreads();

  // ---- 32 MFMAs in 4 blocks of 8, ping-pong prefetch ----
  v4f a0 = {0.f,0.f,0.f,0.f}, a1 = {0.f,0.f,0.f,0.f};
  #pragma unroll
  for (int blk=0; blk<4; ++blk){
    v8bf wn[8];
    if (blk < 3){
      #pragma unroll
      for (int i=0;i<8;++i) wn[i] = ldv(wp + (size_t)((blk+1)*8 + i)*512);
    }
    #pragma unroll
    for (int i=0;i<8;i+=2){
      const int kk = blk*8 + i;
      a0 = MFMA(afrag(lds_h, kk,   lane), w[i],   a0);
      a1 = MFMA(afrag(lds_h, kk+1, lane), w[i+1], a1);
    }
    if (blk < 3){
      #pragma unroll
      for (int i=0;i<8;++i) w[i] = wn[i];
    }
  }
  {
    const v4f a = a0 + a1;
    #pragma unroll
    for (int r=0;r<4;r++) T_W(wave, quad*4+r, l15) = a[r];
  }
  __syncthreads();
  {
    const int rl = tid >> 5, cb = tid & 31;
    const int jt2 = cb >> 4, c = cb & 15;
    const int col = cseg*32 + cb;
    float pr  = T_W(0*2+jt2, rl, c);
    float pz  = T_W(1*2+jt2, rl, c);
    float pin = T_W(2*2+jt2, rl, c);
    float phn = T_W(3*2+jt2, rl, c);
    float rgg = sigm(pr + bi[col] + bh[col]);
    float zg  = sigm(pz + bi[1024+col] + bh[1024+col]);
    float nv  = tanh_(pin + bi[2048+col] + rgg*(phn + bh[2048+col]));
    float hp  = hp16(lds_h, rl, col);
    float hv  = (1.f - zg)*nv + zg*hp;
    dst[(size_t)(rB+rl)*1024 + col] = f2bf(hv);
    if (out_h) out_h[(size_t)(rB+rl)*1024 + col] = hv;
  }
}

// ---------------- host ----------------
extern "C" void kernel_launch(void* const* d_in, const int* in_sizes, int n_in,
                              void* d_out, int out_size, void* d_ws, size_t ws_size,
                              hipStream_t stream)
{
  (void)in_sizes; (void)n_in; (void)out_size; (void)ws_size;
  const float* x     = (const float*)d_in[0];
  const float* masks = (const float*)d_in[1];
  const float* Wih0  = (const float*)d_in[2];
  const float* Whh0  = (const float*)d_in[3];
  const float* bih0  = (const float*)d_in[4];
  const float* bhh0  = (const float*)d_in[5];
  const float* WihR  = (const float*)d_in[6];
  const float* WhhR  = (const float*)d_in[7];
  const float* bihR  = (const float*)d_in[8];
  const float* bhhR  = (const float*)d_in[9];
  const float* Wp    = (const float*)d_in[10];
  const float* bp    = (const float*)d_in[11];
  float* out = (float*)d_out;

  // ws: pad 4096B | hA hB hC (bf16 131072 ea) | packed weights
  bf16* hA      = (bf16*)((char*)d_ws + 4096);
  bf16* hB      = hA + 131072;
  bf16* hC      = hB + 131072;
  bf16* packU   = hC + 131072;         // 8,388,608 elems
  bf16* packL0h = packU + 8388608;     // 3,145,728
  bf16* packL0x = packL0h + 3145728;   // 393,216
  bf16* packImp = packL0x + 393216;    // 131,072

  hipLaunchKernelGGL(init_pk,      dim3(512),  dim3(256), 0, stream, hA);
  hipLaunchKernelGGL(pack_upper_k, dim3(4096), dim3(256), 0, stream, WihR, WhhR, packU);
  hipLaunchKernelGGL(pack_l0h_k,   dim3(1536), dim3(256), 0, stream, Whh0, packL0h);
  hipLaunchKernelGGL(pack_l0x_k,   dim3(192),  dim3(256), 0, stream, Wih0, packL0x);
  hipLaunchKernelGGL(pack_imp_k,   dim3(64),   dim3(256), 0, stream, Wp, packImp);

  for (int t = 0; t < 128; ++t){
    hipLaunchKernelGGL(gru_l0, dim3(256), dim3(512), 0, stream,
        t, x, masks, bih0, bhh0, bp, packL0h, packL0x, packImp, hA, hB, out);
    hipLaunchKernelGGL(gru_up, dim3(256), dim3(512), 0, stream,
        0, t, bihR, bhhR, packU, hB, hC, out);
    hipLaunchKernelGGL(gru_up, dim3(256), dim3(512), 0, stream,
        1, t, bihR, bhhR, packU, hC, hA, out);
  }
}

// Round 13
// 2868.701 us; speedup vs baseline: 1.3789x; 1.0025x over previous
//
#include <hip/hip_runtime.h>
#include <hip/hip_bf16.h>

// GRU-imputation scan (B=128,T=128,D=128,H=1024,L=3), f32 in/out.
// Round 15: R14 (2876 us verified) + the same software-pipelined weight
// prefetch applied to gru_l0's two MFMA loops: IC packImp weights prefetch
// under stage+sync; main packL0h/packL0x weights prefetch under the IC
// T_W/sync/epilogue window; 4x8 ping-pong through both loops.
// gru_up is byte-identical to R14 (clean A/B: only gru_l0 changed).

typedef __hip_bfloat16 bf16;
typedef unsigned int u32;
typedef unsigned short u16;
typedef __attribute__((ext_vector_type(8))) short v8bf;   // 8 x bf16 (16B)
typedef __attribute__((ext_vector_type(4))) float v4f;    // MFMA C/D
typedef __attribute__((ext_vector_type(4))) u32 v4u;

__device__ __forceinline__ float bf2f(bf16 v){ return __bfloat162float(v); }
__device__ __forceinline__ bf16 f2bf(float v){ return __float2bfloat16(v); }
__device__ __forceinline__ float sigm(float x){ return 1.f/(1.f + __expf(-x)); }
__device__ __forceinline__ float tanh_(float x){
  float a = fminf(fmaxf(x, -15.f), 15.f);
  float t = __expf(2.f*a);
  return (t-1.f)/(t+1.f);
}
__device__ __forceinline__ v8bf ldv(const bf16* p){ return *reinterpret_cast<const v8bf*>(p); }

// =================================================================
// Packing kernels (unchanged; validated).
// Fragment unit = 64 lanes x 8 bf16; lane's 8 elems =
//   W[row(j,lane&15)][kk*32 + ((lane>>4)&3)*8 + e]
// =================================================================
__global__ void pack_upper_k(const float* __restrict__ Wih, const float* __restrict__ Whh,
                             bf16* __restrict__ dst){
  int tid = blockIdx.x*256 + threadIdx.x;          // 1,048,576
  int lane = tid & 63;
  int u    = tid >> 6;
  int kk   = u & 31;
  int j    = (u >> 5) & 63;
  int s    = (u >> 11) & 3;
  int l    = u >> 13;
  int n    = j*16 + (lane & 15);
  int k    = kk*32 + ((lane>>4)&3)*8;
  int row  = (s==0) ? n : (s==1 ? 1024+n : 2048+n);
  size_t src = ((size_t)l*3072 + row)*1024 + k;
  size_t o = (size_t)tid*8;
  #pragma unroll
  for (int e=0;e<8;e++){
    float v;
    if (s < 2)      v = Wih[src+e] + Whh[src+e];
    else if (s==2)  v = Wih[src+e];
    else            v = Whh[src+e];
    dst[o+e] = f2bf(v);
  }
}
__global__ void pack_l0h_k(const float* __restrict__ Whh0, bf16* __restrict__ dst){
  int tid = blockIdx.x*256 + threadIdx.x;          // 393,216
  int lane = tid & 63;
  int u  = tid >> 6;
  int kk = u & 31;
  int j  = (u >> 5) & 63;
  int g  = u >> 11;
  int row = g*1024 + j*16 + (lane&15);
  int k   = kk*32 + ((lane>>4)&3)*8;
  size_t src = (size_t)row*1024 + k;
  size_t o = (size_t)tid*8;
  #pragma unroll
  for (int e=0;e<8;e++) dst[o+e] = f2bf(Whh0[src+e]);
}
__global__ void pack_l0x_k(const float* __restrict__ Wih0, bf16* __restrict__ dst){
  int tid = blockIdx.x*256 + threadIdx.x;          // 49,152
  int lane = tid & 63;
  int u  = tid >> 6;
  int kk = u & 3;
  int j  = (u >> 2) & 63;
  int g  = u >> 8;
  int row = g*1024 + j*16 + (lane&15);
  int k   = kk*32 + ((lane>>4)&3)*8;
  size_t src = (size_t)row*128 + k;
  size_t o = (size_t)tid*8;
  #pragma unroll
  for (int e=0;e<8;e++) dst[o+e] = f2bf(Wih0[src+e]);
}
__global__ void pack_imp_k(const float* __restrict__ Wp, bf16* __restrict__ dst){
  int tid = blockIdx.x*256 + threadIdx.x;          // 16,384
  int lane = tid & 63;
  int u  = tid >> 6;
  int kk = u & 31;
  int jj = u >> 5;
  int row = jj*16 + (lane&15);
  int k   = kk*32 + ((lane>>4)&3)*8;
  size_t src = (size_t)row*1024 + k;
  size_t o = (size_t)tid*8;
  #pragma unroll
  for (int e=0;e<8;e++) dst[o+e] = f2bf(Wp[src+e]);
}
__global__ void init_pk(bf16* __restrict__ hA){
  int tid = blockIdx.x*256 + threadIdx.x;          // 131,072
  hA[tid] = f2bf(0.f);                             // h0 = 0
}

// =================================================================
// 16-row fragment layout (validated): lds_h[kk*512 + lane*8] =
//   h[lane&15][kk*32 + (lane>>4)*8 + e]
// =================================================================
__device__ __forceinline__ v8bf afrag(const bf16* lds_h, int kk, int lane){
  return ldv(lds_h + (size_t)kk*512 + (size_t)lane*8);
}
__device__ __forceinline__ float hp16(const bf16* lds_h, int rl, int colh){
  int kk = colh >> 5, q = (colh >> 3) & 3, e = colh & 7;
  return bf2f(lds_h[(size_t)kk*512 + (size_t)(q*16 + rl)*8 + e]);
}

#define MFMA(a,b,c) __builtin_amdgcn_mfma_f32_16x16x32_bf16((a),(b),(c),0,0,0)

// lds2 tile: 16x16 f32 at stride 17 (pad), tile stride 272
#define T_W(w, row, col)  lds2[(w)*272 + (row)*17 + (col)]

// =================================================================
// L0 kernel — R11 structure + pipelined weight prefetch in both loops.
// Grid 256 x 512: cseg = bid&31 (32 cols, cseg%8 = XCD), g = bid>>5 (16 rows).
// =================================================================
__global__ __launch_bounds__(512) void gru_l0(
  const int t,
  const float* __restrict__ x, const float* __restrict__ masks,
  const float* __restrict__ bih0, const float* __restrict__ bhh0,
  const float* __restrict__ bp,
  const bf16* __restrict__ packL0h, const bf16* __restrict__ packL0x,
  const bf16* __restrict__ packImp,
  const bf16* __restrict__ hA, bf16* __restrict__ hB,
  float* __restrict__ out)
{
  const int tid  = threadIdx.x;
  const int lane = tid & 63;
  const int wave = tid >> 6;           // 0..7
  const int l15  = lane & 15;
  const int quad = lane >> 4;
  const int bid  = blockIdx.x;
  const int cseg = bid & 31;
  const int g    = bid >> 5;
  const int rB   = g * 16;

  __shared__ bf16 lds_h[16384];        // 32 KB staged h slice
  __shared__ bf16 lds_c[2048];         // 4 KB staged comp slice
  __shared__ float lds2[12*272];       // ~12.8 KB partial tiles (padded)

  // ---- stage loads first (ds_write's in-order vmcnt waits only on these) ----
  const bf16* g0 = hA + (size_t)(rB + l15)*1024 + wave*128 + quad*8;
  v4u r0 = *(const v4u*)(g0);
  v4u r1 = *(const v4u*)(g0 + 32);
  v4u r2 = *(const v4u*)(g0 + 64);
  v4u r3 = *(const v4u*)(g0 + 96);

  // ---- IC weight prefetch: first 8 packImp fragments (t>=1 only) ----
  const bf16* wpi = packImp + ((size_t)(wave*32))*512 + lane*8;
  v8bf wi[8];
  if (t > 0){
    #pragma unroll
    for (int i=0;i<8;++i) wi[i] = ldv(wpi + (size_t)i*512);
  }

  // ---- LDS writes + sync ----
  {
    bf16* d = lds_h + (size_t)(wave*4)*512 + (size_t)lane*8;
    *(v4u*)(d)        = r0;
    *(v4u*)(d + 512)  = r1;
    *(v4u*)(d + 1024) = r2;
    *(v4u*)(d + 1536) = r3;
  }
  __syncthreads();

  // main-loop weight pointers
  const int ggm = wave >> 1, jtm = wave & 1;            // waves 0..5
  const int jm  = cseg*2 + jtm;
  const bf16* wpm = packL0h + ((size_t)((ggm*64 + jm)*32))*512 + lane*8;
  const int jtx = wave - 6;                             // waves 6..7
  const int jx  = cseg*2 + jtx;
  const bf16* wpx = packL0x + ((size_t)(jx*4))*512 + lane*8;  // gate stride 131072
  v8bf wm[8];
  v8bf wx[4];

  // ---- fused IC: build comp(t-1) slice into lds_c; write out for t>=1 ----
  if (t == 0){
    const int rl = tid >> 5, cb = tid & 31;
    #pragma unroll
    for (int k=0;k<4;++k){
      const int d = cb*4 + k;
      float v = x[(size_t)(rB+rl)*16384 + d];
      lds_c[(size_t)(d>>5)*512 + (size_t)(((d>>3)&3)*16 + rl)*8 + (d&7)] = f2bf(v);
    }
    if (wave < 6){
      #pragma unroll
      for (int i=0;i<8;++i) wm[i] = ldv(wpm + (size_t)i*512);
    } else {
      #pragma unroll
      for (int i=0;i<4;++i) wx[i] = ldv(wpx + (size_t)i*512);
    }
  } else {
    // IC 4x8 ping-pong over packImp (wave = d-tile jt)
    v4f a0 = {0.f,0.f,0.f,0.f}, a1 = {0.f,0.f,0.f,0.f};
    #pragma unroll
    for (int blk=0; blk<4; ++blk){
      v8bf wn[8];
      if (blk < 3){
        #pragma unroll
        for (int i=0;i<8;++i) wn[i] = ldv(wpi + (size_t)((blk+1)*8 + i)*512);
      }
      #pragma unroll
      for (int i=0;i<8;i+=2){
        const int kk = blk*8 + i;
        a0 = MFMA(afrag(lds_h, kk,   lane), wi[i],   a0);
        a1 = MFMA(afrag(lds_h, kk+1, lane), wi[i+1], a1);
      }
      if (blk < 3){
        #pragma unroll
        for (int i=0;i<8;++i) wi[i] = wn[i];
      }
    }
    // issue main-loop prefetch now — hides under T_W/sync/epilogue
    if (wave < 6){
      #pragma unroll
      for (int i=0;i<8;++i) wm[i] = ldv(wpm + (size_t)i*512);
    } else {
      #pragma unroll
      for (int i=0;i<4;++i) wx[i] = ldv(wpx + (size_t)i*512);
    }
    {
      const v4f a = a0 + a1;
      #pragma unroll
      for (int r=0;r<4;r++) T_W(wave, quad*4+r, l15) = a[r];
    }
    __syncthreads();
    // IC epilogue
    const int rl = tid >> 5, cb = tid & 31, tm = t - 1;
    const float m = masks[(size_t)(rB+rl)*128 + tm];
    const bool wr = (cb == cseg);                 // unique writer per 4 cols
    #pragma unroll
    for (int k=0;k<4;++k){
      const int d = cb*4 + k;
      const int djt = d >> 4, c = d & 15;
      float imp = T_W(djt, rl, c) + bp[d];
      float xv  = x[((size_t)(rB+rl)*128 + tm)*128 + d];
      float cv  = m*xv + (1.f - m)*imp;
      lds_c[(size_t)(d>>5)*512 + (size_t)(((d>>3)&3)*16 + rl)*8 + (d&7)] = f2bf(cv);
      if (wr){
        size_t o = ((size_t)(rB+rl)*127 + tm)*128 + d;
        out[131072 + o]  = cv;    // completed
        out[2211840 + o] = imp;   // imputed
      }
    }
  }
  __syncthreads();

  // ---- main L0 matmuls (pipelined) ----
  if (wave < 6){
    v4f a0 = {0.f,0.f,0.f,0.f}, a1 = {0.f,0.f,0.f,0.f};
    #pragma unroll
    for (int blk=0; blk<4; ++blk){
      v8bf wn[8];
      if (blk < 3){
        #pragma unroll
        for (int i=0;i<8;++i) wn[i] = ldv(wpm + (size_t)((blk+1)*8 + i)*512);
      }
      #pragma unroll
      for (int i=0;i<8;i+=2){
        const int kk = blk*8 + i;
        a0 = MFMA(afrag(lds_h, kk,   lane), wm[i],   a0);
        a1 = MFMA(afrag(lds_h, kk+1, lane), wm[i+1], a1);
      }
      if (blk < 3){
        #pragma unroll
        for (int i=0;i<8;++i) wm[i] = wn[i];
      }
    }
    const v4f a = a0 + a1;
    #pragma unroll
    for (int r=0;r<4;r++) T_W(wave, quad*4+r, l15) = a[r];
  } else {
    #pragma unroll
    for (int gg=0; gg<3; ++gg){
      v8bf wn[4];
      if (gg < 2){
        #pragma unroll
        for (int i=0;i<4;++i)
          wn[i] = ldv(wpx + (size_t)(gg+1)*131072 + (size_t)i*512);
      }
      v4f a = {0.f,0.f,0.f,0.f};
      #pragma unroll
      for (int i=0;i<4;++i){
        a = MFMA(ldv(lds_c + (size_t)i*512 + lane*8), wx[i], a);
      }
      if (gg < 2){
        #pragma unroll
        for (int i=0;i<4;++i) wx[i] = wn[i];
      }
      const int slot = 6 + gg*2 + jtx;
      #pragma unroll
      for (int r=0;r<4;r++) T_W(slot, quad*4+r, l15) = a[r];
    }
  }
  __syncthreads();
  {
    const int rl = tid >> 5, cb = tid & 31;
    const int jt = cb >> 4, c = cb & 15;
    const int col = cseg*32 + cb;
    float ghr = T_W(0*2+jt, rl, c);
    float ghz = T_W(1*2+jt, rl, c);
    float ghn = T_W(2*2+jt, rl, c);
    float gir = T_W(6+0*2+jt, rl, c);
    float giz = T_W(6+1*2+jt, rl, c);
    float gin = T_W(6+2*2+jt, rl, c);
    float rgg = sigm(gir + bih0[col]      + ghr + bhh0[col]);
    float zg  = sigm(giz + bih0[1024+col] + ghz + bhh0[1024+col]);
    float nv  = tanh_(gin + bih0[2048+col] + rgg*(ghn + bhh0[2048+col]));
    float hp  = hp16(lds_h, rl, col);
    hB[(size_t)(rB+rl)*1024 + col] = f2bf((1.f - zg)*nv + zg*hp);
  }
}

// =================================================================
// Upper-layer kernel — byte-identical to R14 (verified 2876 us).
// =================================================================
__global__ __launch_bounds__(512) void gru_up(
  const int lay, const int t,
  const float* __restrict__ bihR, const float* __restrict__ bhhR,
  const bf16* __restrict__ packU,
  const bf16* __restrict__ src, bf16* __restrict__ dst,
  float* __restrict__ out)
{
  const int tid  = threadIdx.x;
  const int lane = tid & 63;
  const int wave = tid >> 6;           // 0..7
  const int l15  = lane & 15;
  const int quad = lane >> 4;
  const int bid  = blockIdx.x;
  const int cseg = bid & 31;
  const int g    = bid >> 5;
  const int rB   = g * 16;
  const bf16* packL = packU + (size_t)lay*4194304;
  const float* bi = bihR + lay*3072;
  const float* bh = bhhR + lay*3072;
  float* out_h = (lay == 1 && t == 127) ? out : nullptr;

  __shared__ bf16 lds_h[16384];
  __shared__ float lds2[8*272];

  // ---- stage loads first (in-order vmcnt: ds_write waits only on these) ----
  const bf16* g0 = src + (size_t)(rB + l15)*1024 + wave*128 + quad*8;
  v4u r0 = *(const v4u*)(g0);
  v4u r1 = *(const v4u*)(g0 + 32);
  v4u r2 = *(const v4u*)(g0 + 64);
  v4u r3 = *(const v4u*)(g0 + 96);

  // ---- weight prefetch: first 8 fragments into VGPRs ----
  const int s = wave >> 1, jt = wave & 1;
  const int j = cseg*2 + jt;
  const bf16* wp = packL + ((size_t)((s*64 + j)*32))*512 + lane*8;
  v8bf w[8];
  #pragma unroll
  for (int i=0;i<8;++i) w[i] = ldv(wp + (size_t)i*512);

  // ---- LDS writes + sync ----
  {
    bf16* d = lds_h + (size_t)(wave*4)*512 + (size_t)lane*8;
    *(v4u*)(d)        = r0;
    *(v4u*)(d + 512)  = r1;
    *(v4u*)(d + 1024) = r2;
    *(v4u*)(d + 1536) = r3;
  }
  __syncthreads();

  // ---- 32 MFMAs in 4 blocks of 8, ping-pong prefetch ----
  v4f a0 = {0.f,0.f,0.f,0.f}, a1 = {0.f,0.f,0.f,0.f};
  #pragma unroll
  for (int blk=0; blk<4; ++blk){
    v8bf wn[8];
    if (blk < 3){
      #pragma unroll
      for (int i=0;i<8;++i) wn[i] = ldv(wp + (size_t)((blk+1)*8 + i)*512);
    }
    #pragma unroll
    for (int i=0;i<8;i+=2){
      const int kk = blk*8 + i;
      a0 = MFMA(afrag(lds_h, kk,   lane), w[i],   a0);
      a1 = MFMA(afrag(lds_h, kk+1, lane), w[i+1], a1);
    }
    if (blk < 3){
      #pragma unroll
      for (int i=0;i<8;++i) w[i] = wn[i];
    }
  }
  {
    const v4f a = a0 + a1;
    #pragma unroll
    for (int r=0;r<4;r++) T_W(wave, quad*4+r, l15) = a[r];
  }
  __syncthreads();
  {
    const int rl = tid >> 5, cb = tid & 31;
    const int jt2 = cb >> 4, c = cb & 15;
    const int col = cseg*32 + cb;
    float pr  = T_W(0*2+jt2, rl, c);
    float pz  = T_W(1*2+jt2, rl, c);
    float pin = T_W(2*2+jt2, rl, c);
    float phn = T_W(3*2+jt2, rl, c);
    float rgg = sigm(pr + bi[col] + bh[col]);
    float zg  = sigm(pz + bi[1024+col] + bh[1024+col]);
    float nv  = tanh_(pin + bi[2048+col] + rgg*(phn + bh[2048+col]));
    float hp  = hp16(lds_h, rl, col);
    float hv  = (1.f - zg)*nv + zg*hp;
    dst[(size_t)(rB+rl)*1024 + col] = f2bf(hv);
    if (out_h) out_h[(size_t)(rB+rl)*1024 + col] = hv;
  }
}

// ---------------- host ----------------
extern "C" void kernel_launch(void* const* d_in, const int* in_sizes, int n_in,
                              void* d_out, int out_size, void* d_ws, size_t ws_size,
                              hipStream_t stream)
{
  (void)in_sizes; (void)n_in; (void)out_size; (void)ws_size;
  const float* x     = (const float*)d_in[0];
  const float* masks = (const float*)d_in[1];
  const float* Wih0  = (const float*)d_in[2];
  const float* Whh0  = (const float*)d_in[3];
  const float* bih0  = (const float*)d_in[4];
  const float* bhh0  = (const float*)d_in[5];
  const float* WihR  = (const float*)d_in[6];
  const float* WhhR  = (const float*)d_in[7];
  const float* bihR  = (const float*)d_in[8];
  const float* bhhR  = (const float*)d_in[9];
  const float* Wp    = (const float*)d_in[10];
  const float* bp    = (const float*)d_in[11];
  float* out = (float*)d_out;

  // ws: pad 4096B | hA hB hC (bf16 131072 ea) | packed weights
  bf16* hA      = (bf16*)((char*)d_ws + 4096);
  bf16* hB      = hA + 131072;
  bf16* hC      = hB + 131072;
  bf16* packU   = hC + 131072;         // 8,388,608 elems
  bf16* packL0h = packU + 8388608;     // 3,145,728
  bf16* packL0x = packL0h + 3145728;   // 393,216
  bf16* packImp = packL0x + 393216;    // 131,072

  hipLaunchKernelGGL(init_pk,      dim3(512),  dim3(256), 0, stream, hA);
  hipLaunchKernelGGL(pack_upper_k, dim3(4096), dim3(256), 0, stream, WihR, WhhR, packU);
  hipLaunchKernelGGL(pack_l0h_k,   dim3(1536), dim3(256), 0, stream, Whh0, packL0h);
  hipLaunchKernelGGL(pack_l0x_k,   dim3(192),  dim3(256), 0, stream, Wih0, packL0x);
  hipLaunchKernelGGL(pack_imp_k,   dim3(64),   dim3(256), 0, stream, Wp, packImp);

  for (int t = 0; t < 128; ++t){
    hipLaunchKernelGGL(gru_l0, dim3(256), dim3(512), 0, stream,
        t, x, masks, bih0, bhh0, bp, packL0h, packL0x, packImp, hA, hB, out);
    hipLaunchKernelGGL(gru_up, dim3(256), dim3(512), 0, stream,
        0, t, bihR, bhhR, packU, hB, hC, out);
    hipLaunchKernelGGL(gru_up, dim3(256), dim3(512), 0, stream,
        1, t, bihR, bhhR, packU, hC, hA, out);
  }
}